// Round 4
// baseline (585.898 us; speedup 1.0000x reference)
//
#include <hip/hip_runtime.h>

// PerlinPowerFractal: B=16, H=W=1024, 8 octaves, per-image minmax normalize.
// R4: k2 = single ds_read_b128 per pixel-octave (duplicated column-pair CT),
//     no hrow staging, launch_bounds(256,4) for ILP (VGPR 32 was throttling
//     outstanding LDS reads). k1 = tile-restructured for MLP: 8 independent
//     q-loads + 64 independent hpair byte gathers + coalesced byte stores.

#define HW  1048576       // 1024*1024
#define PSTRIDE 2097152   // 2 * P_COUNT per image
#define PBS 1049088       // hpair bytes per image (1048576+512, 16B-aligned)

struct ZTab { float zf; float w; int Zi; int pad; };

__device__ __forceinline__ float fadef(float t) {
    return t * t * t * (t * (t * 6.0f - 15.0f) + 10.0f);
}
__device__ __forceinline__ unsigned f2ord(float f) {
    unsigned u = __float_as_uint(f);
    return (u & 0x80000000u) ? ~u : (u | 0x80000000u);
}
__device__ __forceinline__ float ord2f(unsigned u) {
    return __uint_as_float((u & 0x80000000u) ? (u ^ 0x80000000u) : ~u);
}
// i mod 255 for 0 <= i < 65536 (256 == 1 mod 255)
__device__ __forceinline__ int mod255(int i) {
    int s = (i & 255) + (i >> 8);
    return s - ((s >= 255) ? 255 : 0);
}

__constant__ const float AW[8] = {
    1.0f, 0.03125f, 9.765625e-4f, 3.0517578125e-5f,
    9.5367431640625e-7f, 2.9802322387695312e-8f,
    9.313225746154785e-10f, 2.9103830456733704e-11f
};

// k0: per-(b,o) z scalars + minmax init. 1 block x 128 threads.
__global__ void ppf_k0(const float* __restrict__ Z, ZTab* __restrict__ zs,
                       unsigned* __restrict__ minmax) {
    int t = threadIdx.x;
    if (t < 128) {
        int b = t >> 3, o = t & 7;
        float z0 = 0.1f * (float)b + Z[0];          // EVOLUTION*b + Z + FRAME
        float freq = (float)(1 << o);
        float nz = (z0 / 100.0f) * freq;
        float fz = floorf(nz);
        ZTab zt;
        zt.Zi = ((int)fz) % 255;
        zt.zf = nz - fz;
        zt.w  = fadef(zt.zf);
        zt.pad = 0;
        zs[t] = zt;
    }
    if (t < 32) {
        minmax[t] = (t & 1) ? 0u : 0xFFFFFFFFu;     // even=min, odd=max
    }
}

// k0b: hpair[b][k] = (p[k]&15) | ((p[k+1]&15)<<4). grid(1025,16) x 256.
__global__ void ppf_k0b(const int* __restrict__ p_all, unsigned char* __restrict__ hp) {
    int idx = blockIdx.x * 256 + threadIdx.x;
    int b = blockIdx.y;
    if (idx < PBS / 4) {
        const int* p = p_all + (size_t)b * PSTRIDE;
        int4 v = ((const int4*)p)[idx];
        int nxt = p[idx * 4 + 4];
        uchar4 o;
        o.x = (unsigned char)((v.x & 15) | ((v.y & 15) << 4));
        o.y = (unsigned char)((v.y & 15) | ((v.z & 15) << 4));
        o.z = (unsigned char)((v.z & 15) | ((v.w & 15) << 4));
        o.w = (unsigned char)((v.w & 15) | ((nxt & 15) << 4));
        ((uchar4*)(hp + (size_t)b * PBS))[idx] = o;
    }
}

// k1: build G[b][o][j=Yi][i=Xi] = hpair[q + Zi_o], q = p[p[i]+j].
// grid(32=j-tile, 16=b) x 256 threads (i). 8 j's per block -> high MLP.
template <int USE_HP>
__global__ void ppf_k1(const int* __restrict__ p_all, const unsigned char* __restrict__ hp,
                       const ZTab* __restrict__ zs, unsigned char* __restrict__ G) {
    int tid = threadIdx.x;          // i = Xi
    int j0 = blockIdx.x * 8;        // j = j0..j0+7
    int b = blockIdx.y;
    const int* p = p_all + (size_t)b * PSTRIDE;
    int sp = p[tid];                // coalesced
    int q[8];
#pragma unroll
    for (int jj = 0; jj < 8; jj++) q[jj] = p[sp + j0 + jj];   // 8 independent loads
    int zi[8];
#pragma unroll
    for (int o = 0; o < 8; o++) zi[o] = zs[b * 8 + o].Zi;     // uniform s_loads

    unsigned char h[8][8];
    if (USE_HP) {
        const unsigned char* hb = hp + (size_t)b * PBS;
#pragma unroll
        for (int jj = 0; jj < 8; jj++)
#pragma unroll
            for (int o = 0; o < 8; o++)
                h[jj][o] = hb[q[jj] + zi[o]];                 // 64 independent loads
    } else {
#pragma unroll
        for (int jj = 0; jj < 8; jj++)
#pragma unroll
            for (int o = 0; o < 8; o++) {
                int h0 = p[q[jj] + zi[o]] & 15;
                int h1 = p[q[jj] + zi[o] + 1] & 15;
                h[jj][o] = (unsigned char)(h0 | (h1 << 4));
            }
    }
    unsigned char* Gb = G + ((size_t)b << 19);
#pragma unroll
    for (int o = 0; o < 8; o++)
#pragma unroll
        for (int jj = 0; jj < 8; jj++)
            Gb[((size_t)o << 16) + ((j0 + jj) << 8) + tid] = h[jj][o];  // coalesced
}

// k1b: per-(b,o) 256-entry float4 coef table: grad folded with z-lerp.
// F(byte; x,y) = A*x + CY*y + CZ. grid(8=o, 16=b) x 256 (byte value).
__global__ void ppf_k1b(const ZTab* __restrict__ zs, float4* __restrict__ TgF4) {
    int beta = threadIdx.x, o = blockIdx.x, b = blockIdx.y;
    ZTab z = zs[b * 8 + o];
    float w = z.w, zf = z.zf;
    float A = 0.f, CY = 0.f, CZ = 0.f;
#pragma unroll
    for (int k = 0; k < 2; k++) {
        int   h  = k ? (beta >> 4) : (beta & 15);
        float wk = k ? w : (1.0f - w);
        float zk = k ? (zf - 1.0f) : zf;
        float s1 = (h & 1) ? -1.f : 1.f;
        float s2 = (h & 2) ? -1.f : 1.f;
        bool  vx = (h == 12) || (h == 14);
        float a  = ((h < 8) ? s1 : 0.f) + (vx ? s2 : 0.f);
        float cy = ((h >= 8) ? s1 : 0.f) + ((h < 4) ? s2 : 0.f);
        float cz = (h >= 4 && !vx) ? s2 : 0.f;
        A  = fmaf(wk, a, A);
        CY = fmaf(wk, cy, CY);
        CZ = fmaf(wk * zk, cz, CZ);
    }
    TgF4[(b * 8 + o) * 256 + beta] = make_float4(A, CY, CZ, 0.f);
}

// k2: main kernel. grid(1024=row, 16=b) x 256 threads; 4 pixels/thread.
// LDS = CTd 32 KB -> 4 blocks/CU; VGPR budget 128 for deep load hoisting.
__launch_bounds__(256, 4)
__global__ void ppf_k2(const unsigned char* __restrict__ G,
                       const float4* __restrict__ TgF4,
                       const float* __restrict__ X, const float* __restrict__ Y,
                       float* __restrict__ out, unsigned* __restrict__ minmax) {
    __shared__ float4 CTd[2048];    // [o][col]: {CA(c),CB(c),CA(c+1),CB(c+1)} * aw
    __shared__ float smn[4], smx[4];

    const int tid = threadIdx.x;
    const int r = blockIdx.x, b = blockIdx.y;
    const float X0 = X[0], Y0 = Y[0];
    const float ty = ((float)r + Y0) / 100.0f;

    // build duplicated column table; G rows read directly (coalesced, L2-hot)
    float2* ctd2 = (float2*)CTd;
#pragma unroll
    for (int o = 0; o < 8; o++) {
        float y  = ty * (float)(1 << o);
        float fy = floorf(y);
        float yf = y - fy, ym1 = yf - 1.0f;
        float v  = fadef(yf);
        int Yi = mod255((int)y);
        const unsigned char* Gr = G + (((size_t)(b * 8 + o)) << 16) + (Yi << 8) + tid;
        int h0 = Gr[0];
        int h1 = Gr[256];
        const float4* tg = TgF4 + ((b * 8 + o) << 8);
        float4 g0 = tg[h0];
        float4 g1 = tg[h1];
        float CA = g0.x + v * (g1.x - g0.x);
        float B0 = fmaf(g0.y, yf,  g0.z);
        float B1 = fmaf(g1.y, ym1, g1.z);
        float CB = B0 + v * (B1 - B0);
        float aw = AW[o];
        float2 cc = make_float2(CA * aw, CB * aw);
        ctd2[(o * 256 + tid) * 2] = cc;                      // CTd[o][tid].xy
        if (tid > 0) ctd2[(o * 256 + tid - 1) * 2 + 1] = cc; // CTd[o][tid-1].zw
    }
    __syncthreads();

    float txs[4], accv[4];
#pragma unroll
    for (int i = 0; i < 4; i++) {
        txs[i] = ((float)(tid + 256 * i) + X0) / 100.0f;
        accv[i] = 0.0f;
    }

#pragma unroll
    for (int o = 0; o < 8; o++) {
        const float4* cto = CTd + o * 256;
#pragma unroll
        for (int i = 0; i < 4; i++) {
            float x   = txs[i];
            float fx  = floorf(x);
            float xf  = x - fx, xm1 = xf - 1.0f;
            int   Xi  = mod255((int)x);
            float t2  = xf * xf;
            float m   = fmaf(xf, 6.0f, -15.0f);
            m         = fmaf(xf, m, 10.0f);
            float u   = t2 * xf * m;
            float4 c  = cto[Xi];                 // single ds_read_b128
            float P   = fmaf(c.x, xf,  c.y);
            float Q   = fmaf(c.z, xm1, c.w);
            accv[i]  += P;
            accv[i]   = fmaf(u, Q - P, accv[i]); // += aw * noise
            txs[i]    = x + x;                   // exact *2 for next octave
        }
    }

    // store (coalesced: thread t writes pixels t, t+256, t+512, t+768 of row r)
    size_t obase = ((size_t)b << 20) + ((size_t)r << 10) + tid;
#pragma unroll
    for (int i = 0; i < 4; i++) out[obase + 256 * i] = accv[i];

    // block min/max -> one atomic pair per block
    float mn = fminf(fminf(accv[0], accv[1]), fminf(accv[2], accv[3]));
    float mx = fmaxf(fmaxf(accv[0], accv[1]), fmaxf(accv[2], accv[3]));
#pragma unroll
    for (int off = 32; off > 0; off >>= 1) {
        mn = fminf(mn, __shfl_down(mn, off));
        mx = fmaxf(mx, __shfl_down(mx, off));
    }
    if ((tid & 63) == 0) { smn[tid >> 6] = mn; smx[tid >> 6] = mx; }
    __syncthreads();
    if (tid == 0) {
        mn = fminf(fminf(smn[0], smn[1]), fminf(smn[2], smn[3]));
        mx = fmaxf(fmaxf(smx[0], smx[1]), fmaxf(smx[2], smx[3]));
        atomicMin(&minmax[2 * b],     f2ord(mn));
        atomicMax(&minmax[2 * b + 1], f2ord(mx));
    }
}

// k3: normalize in place. grid(1024, 16=b) x 256 threads, float4.
__global__ void ppf_k3(float* __restrict__ out, const unsigned* __restrict__ minmax) {
    int b = blockIdx.y;
    int idx = blockIdx.x * 256 + threadIdx.x;
    float mn = ord2f(minmax[2 * b]);
    float mx = ord2f(minmax[2 * b + 1]);
    float s = 1.0f / (mx - mn);
    float4* o4 = (float4*)(out + (size_t)b * HW);
    float4 v = o4[idx];
    v.x = (v.x - mn) * s;
    v.y = (v.y - mn) * s;
    v.z = (v.z - mn) * s;
    v.w = (v.w - mn) * s;
    o4[idx] = v;
}

extern "C" void kernel_launch(void* const* d_in, const int* in_sizes, int n_in,
                              void* d_out, int out_size, void* d_ws, size_t ws_size,
                              hipStream_t stream) {
    const int*   p_all = (const int*)d_in[0];
    const float* X     = (const float*)d_in[1];
    const float* Y     = (const float*)d_in[2];
    const float* Z     = (const float*)d_in[3];
    float* out = (float*)d_out;
    char* ws = (char*)d_ws;

    // full layout: G 8MB | hpair 16*PBS | zs 4KB | mm 4KB | TgF4 512KB
    const size_t OFF_HP = 8388608;
    const size_t OFF_ZS_FULL = OFF_HP + (size_t)16 * PBS;   // 25173824... (16*1049088=16785408) -> 25174016
    const size_t NEED_FULL   = OFF_ZS_FULL + 8192 + 524288;
    bool full = (ws_size >= NEED_FULL);
    size_t off_zs = full ? OFF_ZS_FULL : OFF_HP;

    unsigned char* G  = (unsigned char*)ws;
    unsigned char* hp = (unsigned char*)(ws + OFF_HP);
    ZTab*     zs      = (ZTab*)    (ws + off_zs);
    unsigned* minmax  = (unsigned*)(ws + off_zs + 4096);
    float4*   TgF4    = (float4*)  (ws + off_zs + 8192);

    ppf_k0<<<1, 128, 0, stream>>>(Z, zs, minmax);
    if (full) {
        ppf_k0b<<<dim3(1025, 16), 256, 0, stream>>>(p_all, hp);
        ppf_k1<1><<<dim3(32, 16), 256, 0, stream>>>(p_all, hp, zs, G);
    } else {
        ppf_k1<0><<<dim3(32, 16), 256, 0, stream>>>(p_all, hp, zs, G);
    }
    ppf_k1b<<<dim3(8, 16), 256, 0, stream>>>(zs, TgF4);
    ppf_k2<<<dim3(1024, 16), 256, 0, stream>>>(G, TgF4, X, Y, out, minmax);
    ppf_k3<<<dim3(1024, 16), 256, 0, stream>>>(out, minmax);
}

// Round 5
// 584.575 us; speedup vs baseline: 1.0023x; 1.0023x over previous
//
#include <hip/hip_runtime.h>

// PerlinPowerFractal: B=16, H=W=1024, 8 octaves, per-image minmax normalize.
// R5: k2 latency fix — per pixel, batch ALL 16 ds_read_b64 (8 octaves x 2
//     corners) before the math (16-deep MLP per wave), float2 CT (16 KB LDS,
//     conflict-free), launch_bounds(256,5) so the load batch fits in VGPRs.

#define HW  1048576       // 1024*1024
#define PSTRIDE 2097152   // 2 * P_COUNT per image
#define PBS 1049088       // hpair bytes per image (1048576+512, 16B-aligned)

struct ZTab { float zf; float w; int Zi; int pad; };

__device__ __forceinline__ float fadef(float t) {
    return t * t * t * (t * (t * 6.0f - 15.0f) + 10.0f);
}
__device__ __forceinline__ unsigned f2ord(float f) {
    unsigned u = __float_as_uint(f);
    return (u & 0x80000000u) ? ~u : (u | 0x80000000u);
}
__device__ __forceinline__ float ord2f(unsigned u) {
    return __uint_as_float((u & 0x80000000u) ? (u ^ 0x80000000u) : ~u);
}
// i mod 255 for 0 <= i < 65536 (256 == 1 mod 255); result in [0,254]
__device__ __forceinline__ int mod255(int i) {
    int s = (i & 255) + (i >> 8);
    return s - ((s >= 255) ? 255 : 0);
}

__constant__ const float AW[8] = {
    1.0f, 0.03125f, 9.765625e-4f, 3.0517578125e-5f,
    9.5367431640625e-7f, 2.9802322387695312e-8f,
    9.313225746154785e-10f, 2.9103830456733704e-11f
};

// k0: per-(b,o) z scalars + minmax init. 1 block x 128 threads.
__global__ void ppf_k0(const float* __restrict__ Z, ZTab* __restrict__ zs,
                       unsigned* __restrict__ minmax) {
    int t = threadIdx.x;
    if (t < 128) {
        int b = t >> 3, o = t & 7;
        float z0 = 0.1f * (float)b + Z[0];          // EVOLUTION*b + Z + FRAME
        float freq = (float)(1 << o);
        float nz = (z0 / 100.0f) * freq;
        float fz = floorf(nz);
        ZTab zt;
        zt.Zi = ((int)fz) % 255;
        zt.zf = nz - fz;
        zt.w  = fadef(zt.zf);
        zt.pad = 0;
        zs[t] = zt;
    }
    if (t < 32) {
        minmax[t] = (t & 1) ? 0u : 0xFFFFFFFFu;     // even=min, odd=max
    }
}

// k0b: hpair[b][k] = (p[k]&15) | ((p[k+1]&15)<<4). grid(1025,16) x 256.
__global__ void ppf_k0b(const int* __restrict__ p_all, unsigned char* __restrict__ hp) {
    int idx = blockIdx.x * 256 + threadIdx.x;
    int b = blockIdx.y;
    if (idx < PBS / 4) {
        const int* p = p_all + (size_t)b * PSTRIDE;
        int4 v = ((const int4*)p)[idx];
        int nxt = p[idx * 4 + 4];
        uchar4 o;
        o.x = (unsigned char)((v.x & 15) | ((v.y & 15) << 4));
        o.y = (unsigned char)((v.y & 15) | ((v.z & 15) << 4));
        o.z = (unsigned char)((v.z & 15) | ((v.w & 15) << 4));
        o.w = (unsigned char)((v.w & 15) | ((nxt & 15) << 4));
        ((uchar4*)(hp + (size_t)b * PBS))[idx] = o;
    }
}

// k1: build G[b][o][j=Yi][i=Xi] = hpair[q + Zi_o], q = p[p[i]+j].
// grid(32=j-tile, 16=b) x 256 threads (i). 8 j's per block -> high MLP.
template <int USE_HP>
__global__ void ppf_k1(const int* __restrict__ p_all, const unsigned char* __restrict__ hp,
                       const ZTab* __restrict__ zs, unsigned char* __restrict__ G) {
    int tid = threadIdx.x;          // i = Xi
    int j0 = blockIdx.x * 8;        // j = j0..j0+7
    int b = blockIdx.y;
    const int* p = p_all + (size_t)b * PSTRIDE;
    int sp = p[tid];                // coalesced
    int q[8];
#pragma unroll
    for (int jj = 0; jj < 8; jj++) q[jj] = p[sp + j0 + jj];   // 8 independent loads
    int zi[8];
#pragma unroll
    for (int o = 0; o < 8; o++) zi[o] = zs[b * 8 + o].Zi;     // uniform s_loads

    unsigned char h[8][8];
    if (USE_HP) {
        const unsigned char* hb = hp + (size_t)b * PBS;
#pragma unroll
        for (int jj = 0; jj < 8; jj++)
#pragma unroll
            for (int o = 0; o < 8; o++)
                h[jj][o] = hb[q[jj] + zi[o]];                 // 64 independent loads
    } else {
#pragma unroll
        for (int jj = 0; jj < 8; jj++)
#pragma unroll
            for (int o = 0; o < 8; o++) {
                int h0 = p[q[jj] + zi[o]] & 15;
                int h1 = p[q[jj] + zi[o] + 1] & 15;
                h[jj][o] = (unsigned char)(h0 | (h1 << 4));
            }
    }
    unsigned char* Gb = G + ((size_t)b << 19);
#pragma unroll
    for (int o = 0; o < 8; o++)
#pragma unroll
        for (int jj = 0; jj < 8; jj++)
            Gb[((size_t)o << 16) + ((j0 + jj) << 8) + tid] = h[jj][o];  // coalesced
}

// k1b: per-(b,o) 256-entry float4 coef table: grad folded with z-lerp.
// F(byte; x,y) = A*x + CY*y + CZ. grid(8=o, 16=b) x 256 (byte value).
__global__ void ppf_k1b(const ZTab* __restrict__ zs, float4* __restrict__ TgF4) {
    int beta = threadIdx.x, o = blockIdx.x, b = blockIdx.y;
    ZTab z = zs[b * 8 + o];
    float w = z.w, zf = z.zf;
    float A = 0.f, CY = 0.f, CZ = 0.f;
#pragma unroll
    for (int k = 0; k < 2; k++) {
        int   h  = k ? (beta >> 4) : (beta & 15);
        float wk = k ? w : (1.0f - w);
        float zk = k ? (zf - 1.0f) : zf;
        float s1 = (h & 1) ? -1.f : 1.f;
        float s2 = (h & 2) ? -1.f : 1.f;
        bool  vx = (h == 12) || (h == 14);
        float a  = ((h < 8) ? s1 : 0.f) + (vx ? s2 : 0.f);
        float cy = ((h >= 8) ? s1 : 0.f) + ((h < 4) ? s2 : 0.f);
        float cz = (h >= 4 && !vx) ? s2 : 0.f;
        A  = fmaf(wk, a, A);
        CY = fmaf(wk, cy, CY);
        CZ = fmaf(wk * zk, cz, CZ);
    }
    TgF4[(b * 8 + o) * 256 + beta] = make_float4(A, CY, CZ, 0.f);
}

// k2: main kernel. grid(1024=row, 16=b) x 256 threads; 4 pixels/thread.
// LDS = CT 16 KB; per pixel: batch all 16 ds_read_b64, then math.
__launch_bounds__(256, 5)
__global__ void ppf_k2(const unsigned char* __restrict__ G,
                       const float4* __restrict__ TgF4,
                       const float* __restrict__ X, const float* __restrict__ Y,
                       float* __restrict__ out, unsigned* __restrict__ minmax) {
    __shared__ float2 CT[2048];     // [o][col] = (CA, CB) * aw
    __shared__ float smn[4], smx[4];

    const int tid = threadIdx.x;
    const int r = blockIdx.x, b = blockIdx.y;
    const float X0 = X[0], Y0 = Y[0];
    const float ty = ((float)r + Y0) / 100.0f;

    // build column table; G rows read directly (coalesced, L2-hot).
    // P(col c; x) = CA*x + CB = lerp(v, F(h0; x, yf), F(h1; x, ym1)), scaled by aw.
#pragma unroll
    for (int o = 0; o < 8; o++) {
        float y  = ty * (float)(1 << o);
        float fy = floorf(y);
        float yf = y - fy, ym1 = yf - 1.0f;
        float v  = fadef(yf);
        int Yi = mod255((int)y);
        const unsigned char* Gr = G + (((size_t)(b * 8 + o)) << 16) + (Yi << 8) + tid;
        int h0 = Gr[0];
        int h1 = Gr[256];
        const float4* tg = TgF4 + ((b * 8 + o) << 8);
        float4 g0 = tg[h0];
        float4 g1 = tg[h1];
        float CA = g0.x + v * (g1.x - g0.x);
        float B0 = fmaf(g0.y, yf,  g0.z);
        float B1 = fmaf(g1.y, ym1, g1.z);
        float CB = B0 + v * (B1 - B0);
        float aw = AW[o];
        CT[o * 256 + tid] = make_float2(CA * aw, CB * aw);   // stride-8B: conflict-free
    }
    __syncthreads();

    float accv[4];
#pragma unroll
    for (int i = 0; i < 4; i++) {
        float x0 = ((float)(tid + 256 * i) + X0) / 100.0f;

        // phase 1: compute all indices, issue all 16 LDS loads (16-deep MLP)
        float xfv[8];
        float2 c0[8], c1[8];
#pragma unroll
        for (int o = 0; o < 8; o++) {
            float x  = x0 * (float)(1 << o);
            int   ix = (int)x;                  // x > 0: trunc == floor
            xfv[o]   = x - (float)ix;
            int   Xi = mod255(ix);
            const float2* cto = CT + o * 256 + Xi;
            c0[o] = cto[0];                     // ds_read_b64
            c1[o] = cto[1];                     // ds_read_b64 offset:8
        }

        // phase 2: pure VALU
        float acc = 0.0f;
#pragma unroll
        for (int o = 0; o < 8; o++) {
            float xf = xfv[o];
            float t2 = xf * xf;
            float m  = fmaf(xf, 6.0f, -15.0f);
            m        = fmaf(xf, m, 10.0f);
            float u  = t2 * xf * m;
            float P  = fmaf(c0[o].x, xf,        c0[o].y);
            float Q  = fmaf(c1[o].x, xf - 1.0f, c1[o].y);
            acc      = fmaf(u, Q - P, acc + P); // += aw * noise
        }
        accv[i] = acc;
    }

    // store (coalesced: thread t writes pixels t, t+256, t+512, t+768 of row r)
    size_t obase = ((size_t)b << 20) + ((size_t)r << 10) + tid;
#pragma unroll
    for (int i = 0; i < 4; i++) out[obase + 256 * i] = accv[i];

    // block min/max -> one atomic pair per block
    float mn = fminf(fminf(accv[0], accv[1]), fminf(accv[2], accv[3]));
    float mx = fmaxf(fmaxf(accv[0], accv[1]), fmaxf(accv[2], accv[3]));
#pragma unroll
    for (int off = 32; off > 0; off >>= 1) {
        mn = fminf(mn, __shfl_down(mn, off));
        mx = fmaxf(mx, __shfl_down(mx, off));
    }
    if ((tid & 63) == 0) { smn[tid >> 6] = mn; smx[tid >> 6] = mx; }
    __syncthreads();
    if (tid == 0) {
        mn = fminf(fminf(smn[0], smn[1]), fminf(smn[2], smn[3]));
        mx = fmaxf(fmaxf(smx[0], smx[1]), fmaxf(smx[2], smx[3]));
        atomicMin(&minmax[2 * b],     f2ord(mn));
        atomicMax(&minmax[2 * b + 1], f2ord(mx));
    }
}

// k3: normalize in place. grid(1024, 16=b) x 256 threads, float4.
__global__ void ppf_k3(float* __restrict__ out, const unsigned* __restrict__ minmax) {
    int b = blockIdx.y;
    int idx = blockIdx.x * 256 + threadIdx.x;
    float mn = ord2f(minmax[2 * b]);
    float mx = ord2f(minmax[2 * b + 1]);
    float s = 1.0f / (mx - mn);
    float4* o4 = (float4*)(out + (size_t)b * HW);
    float4 v = o4[idx];
    v.x = (v.x - mn) * s;
    v.y = (v.y - mn) * s;
    v.z = (v.z - mn) * s;
    v.w = (v.w - mn) * s;
    o4[idx] = v;
}

extern "C" void kernel_launch(void* const* d_in, const int* in_sizes, int n_in,
                              void* d_out, int out_size, void* d_ws, size_t ws_size,
                              hipStream_t stream) {
    const int*   p_all = (const int*)d_in[0];
    const float* X     = (const float*)d_in[1];
    const float* Y     = (const float*)d_in[2];
    const float* Z     = (const float*)d_in[3];
    float* out = (float*)d_out;
    char* ws = (char*)d_ws;

    // full layout: G 8MB | hpair 16*PBS | zs 4KB | mm 4KB | TgF4 512KB
    const size_t OFF_HP = 8388608;
    const size_t OFF_ZS_FULL = OFF_HP + (size_t)16 * PBS;
    const size_t NEED_FULL   = OFF_ZS_FULL + 8192 + 524288;
    bool full = (ws_size >= NEED_FULL);
    size_t off_zs = full ? OFF_ZS_FULL : OFF_HP;

    unsigned char* G  = (unsigned char*)ws;
    unsigned char* hp = (unsigned char*)(ws + OFF_HP);
    ZTab*     zs      = (ZTab*)    (ws + off_zs);
    unsigned* minmax  = (unsigned*)(ws + off_zs + 4096);
    float4*   TgF4    = (float4*)  (ws + off_zs + 8192);

    ppf_k0<<<1, 128, 0, stream>>>(Z, zs, minmax);
    if (full) {
        ppf_k0b<<<dim3(1025, 16), 256, 0, stream>>>(p_all, hp);
        ppf_k1<1><<<dim3(32, 16), 256, 0, stream>>>(p_all, hp, zs, G);
    } else {
        ppf_k1<0><<<dim3(32, 16), 256, 0, stream>>>(p_all, hp, zs, G);
    }
    ppf_k1b<<<dim3(8, 16), 256, 0, stream>>>(zs, TgF4);
    ppf_k2<<<dim3(1024, 16), 256, 0, stream>>>(G, TgF4, X, Y, out, minmax);
    ppf_k3<<<dim3(1024, 16), 256, 0, stream>>>(out, minmax);
}